// Round 7
// baseline (181.500 us; speedup 1.0000x reference)
//
#include <hip/hip_runtime.h>

typedef unsigned short u16;
typedef unsigned int u32;
typedef __bf16 bf16x8 __attribute__((ext_vector_type(8)));
typedef float f32x4 __attribute__((ext_vector_type(4)));

#define DEV __device__ __forceinline__

// Problem constants (B,T,D_MODEL,H) = (2,2048,1024,16)
constexpr int BB = 2;
constexpr int TT = 2048;
constexpr int CD = 1024;
constexpr int HH = 16;
constexpr int DH = 64;
constexpr int BT = BB * TT;   // 4096

// softmax scale 1/8 folded with log2(e): S' = S/8*log2e, exp(x)=exp2(x')
#define QSCALE 0.18033688011112042f

// Native bf16 convert (RTNE): compiler packs pairs into v_cvt_pk_bf16_f32.
DEV u16 f2bf(float f) {
    return __builtin_bit_cast(u16, (__bf16)f);
}

DEV f32x4 mfma16(bf16x8 a, bf16x8 b, f32x4 c) {
    return __builtin_amdgcn_mfma_f32_16x16x32_bf16(a, b, c, 0, 0, 0);
}

// Async global->LDS, 16B per lane: LDS dest = wave-uniform base + lane*16.
DEV void gld_lds16(u16* lds, const u16* g) {
    __builtin_amdgcn_global_load_lds(
        (const __attribute__((address_space(1))) unsigned int*)g,
        (__attribute__((address_space(3))) unsigned int*)lds, 16, 0, 0);
}

// ---------------------------------------------------------------------------
// Fused preprocessing (single launch):
//   blocks [0,2048):      x fp32 -> bf16           (4096x1024)
//   blocks [2048,5120):   W_qkv (1024x3072) -> transposed bf16 (3072x1024)
//   blocks [5120,6144):   W_o   (1024x1024) -> transposed bf16 (1024x1024)
// ---------------------------------------------------------------------------
__global__ __launch_bounds__(256)
void prep_kernel(const float* __restrict__ x, u16* __restrict__ xb,
                 const float* __restrict__ Wqkv, u16* __restrict__ WqkvT,
                 const float* __restrict__ Wo, u16* __restrict__ WoT) {
    const int tid = threadIdx.x;
    int blk = blockIdx.x;
    if (blk < 2048) {                       // convert job
        const int i = (blk * 256 + tid) * 8;
        float4 a = *(const float4*)&x[i];
        float4 b = *(const float4*)&x[i + 4];
        u16 t[8];
        t[0] = f2bf(a.x); t[1] = f2bf(a.y); t[2] = f2bf(a.z); t[3] = f2bf(a.w);
        t[4] = f2bf(b.x); t[5] = f2bf(b.y); t[6] = f2bf(b.z); t[7] = f2bf(b.w);
        *(uint4*)&xb[i] = *(const uint4*)t;
        return;                             // whole block exits (no barrier)
    }
    __shared__ u16 tile[32][33];
    const float* in; u16* out; int rows, cols, bx, by;
    if (blk < 5120) { blk -= 2048; in = Wqkv; out = WqkvT; rows = 1024; cols = 3072; bx = blk % 96; by = blk / 96; }
    else            { blk -= 5120; in = Wo;   out = WoT;   rows = 1024; cols = 1024; bx = blk % 32; by = blk / 32; }
    const int c0 = bx * 32, r0 = by * 32;
    const int tx = tid & 31, ty = tid >> 5;
    #pragma unroll
    for (int i = ty; i < 32; i += 8)
        tile[i][tx] = f2bf(in[(r0 + i) * cols + (c0 + tx)]);
    __syncthreads();
    #pragma unroll
    for (int i = ty; i < 32; i += 8)
        out[(c0 + i) * rows + (r0 + tx)] = tile[tx][i];
}

// ---------------------------------------------------------------------------
// GEMM v3: 3-deep pipelined staging + counted vmcnt (T4) + chunk-XOR LDS
// swizzle (T2).  C[M][N] = A[M][K] * Bt[N][K]^T, bf16->fp32 acc.
// BM=128, BN template (128 or 64), BK=32.  (Unchanged: conflicts measured 0;
// timing at the 2-phase-class structural plateau.)
// ---------------------------------------------------------------------------
template <int EPI, int BN, int GX>
__global__ __launch_bounds__(256)
void gemm_db(const u16* __restrict__ A, const u16* __restrict__ Bt,
             u16* __restrict__ out0, u16* __restrict__ out1,
             u16* __restrict__ out2, float* __restrict__ outf,
             int M, int N, int K) {
    constexpr int BM = 128, BK = 32, AST = 32;
    constexpr int NT = BN / 32;             // n-tiles per wave
    constexpr int NBLK = GX * 32;           // M/BM = 32 always here
    constexpr int CPX = NBLK / 8;           // blocks per XCD chunk
    __shared__ alignas(16) u16 As[3][BM * AST];
    __shared__ alignas(16) u16 Bs[3][BN * AST];

    const int tid  = threadIdx.x;
    const int wave = tid >> 6, lane = tid & 63;
    const int quad = lane >> 4, l16 = lane & 15;
    const int wm = (wave & 1) * 64, wn = (wave >> 1) * (BN / 2);

    // T1: XCD-aware chunked swizzle (bijective since NBLK % 8 == 0)
    int bid = (int)blockIdx.x;
    bid = (bid & 7) * CPX + (bid >> 3);
    const int bx = bid % GX, by = bid / GX;
    const int m0 = by * BM, n0 = bx * BN;

    // DMA staging: one instr = 64 lanes x 16B = 16 rows x 64B.
    // T2 pre-swizzled global source chunk.
    const int srowA = wave * 32 + (lane >> 2);
    const int srowB = wave * (BN / 4) + (lane >> 2);
    const int scol  = (((lane & 3) ^ ((lane >> 3) & 3))) * 8;
    const u16* ga0 = A  + (size_t)(m0 + srowA) * K + scol;
    const u16* ga1 = ga0 + (size_t)16 * K;
    const u16* gb0 = Bt + (size_t)(n0 + srowB) * K + scol;
    const u16* gb1 = gb0 + (size_t)16 * K;

    auto stage = [&](int buf, int k0) {
        gld_lds16(&As[buf][wave * 1024],           ga0 + k0);
        gld_lds16(&As[buf][wave * 1024 + 512],     ga1 + k0);
        gld_lds16(&Bs[buf][wave * (BN * 8)],       gb0 + k0);
        if constexpr (BN == 128)
            gld_lds16(&Bs[buf][wave * (BN * 8) + 512], gb1 + k0);
    };
    // mid-loop counted wait: one stage (LPS loads) stays in flight
    auto wait_lps = [&]() {
        if constexpr (BN == 128) asm volatile("s_waitcnt vmcnt(4)" ::: "memory");
        else                     asm volatile("s_waitcnt vmcnt(3)" ::: "memory");
    };

    f32x4 acc[4][NT] = {};

    stage(0, 0);
    stage(1, BK);
    wait_lps();                              // step-0 buffers landed
    __builtin_amdgcn_s_barrier();

    const int sx = ((l16 >> 1) & 3) * 8;     // T2 read-side XOR term
    const int NS = K / BK;
    int cb = 0;                              // current buffer
    for (int t = 0; t < NS; ++t) {
        const bool pf = (t + 2 < NS);
        int sb = cb + 2; if (sb >= 3) sb -= 3;
        if (pf) stage(sb, (t + 2) * BK);

        bf16x8 fa[4], fb[NT];
        #pragma unroll
        for (int mt = 0; mt < 4; ++mt)
            fa[mt] = *(const bf16x8*)
                &As[cb][(wm + mt * 16 + l16) * AST + (quad * 8 ^ sx)];
        #pragma unroll
        for (int nt = 0; nt < NT; ++nt)
            fb[nt] = *(const bf16x8*)
                &Bs[cb][(wn + nt * 16 + l16) * AST + (quad * 8 ^ sx)];
        #pragma unroll
        for (int mt = 0; mt < 4; ++mt)
            #pragma unroll
            for (int nt = 0; nt < NT; ++nt)
                acc[mt][nt] = mfma16(fa[mt], fb[nt], acc[mt][nt]);

        if (pf) wait_lps();                  // drain stage for step t+1 only
        else    asm volatile("s_waitcnt vmcnt(0)" ::: "memory");
        __builtin_amdgcn_s_barrier();
        cb = (cb + 1 == 3) ? 0 : cb + 1;
    }

    // Epilogue. C/D layout: row = quad*4+reg, col = l16.
    #pragma unroll
    for (int mt = 0; mt < 4; ++mt) {
        #pragma unroll
        for (int nt = 0; nt < NT; ++nt) {
            #pragma unroll
            for (int reg = 0; reg < 4; ++reg) {
                const int r = m0 + wm + mt * 16 + quad * 4 + reg;
                const int c = n0 + wn + nt * 16 + l16;
                if (EPI == 0) {
                    outf[(size_t)r * N + c] = acc[mt][nt][reg];
                } else {
                    const int which = c >> 10;       // 0=q 1=k 2=v
                    const int cc = c & 1023;
                    const int h = cc >> 6, d = cc & 63;
                    const int b = r >> 11, t = r & 2047;
                    const int bh = b * HH + h;
                    if (which == 0) {
                        out0[((size_t)bh * TT + t) * DH + d] =
                            f2bf(acc[mt][nt][reg] * QSCALE);
                    } else if (which == 1) {
                        out1[((size_t)bh * TT + t) * DH + d] = f2bf(acc[mt][nt][reg]);
                    } else {
                        out2[((size_t)bh * DH + d) * TT + t] = f2bf(acc[mt][nt][reg]);
                    }
                }
            }
        }
    }
}

// ---------------------------------------------------------------------------
// Flash attention v7 (causal): v5 core (64-row q-tile, 4 waves, S^T form,
// paired-key full-K=32 PV) + flash-decode KV-SPLIT.
// The v5/v6 critical path was the longest q-tile: 32 serial KV-chunk steps.
// Split every qt>=16 tile into two KV segments handled by independent
// blocks producing partials (O, m, l); a combine kernel merges them.
// Longest task 32 -> 16 steps; grid 1024 -> 1536 over 1024 CU-slots
// (4 blocks/CU, LDS 36.9KB) -> real refill queue; lengths 1..16 dispatched
// longest-first via a static table.  bh = bid&31 keeps bh%8 == XCD.
// ---------------------------------------------------------------------------
constexpr int KST = 72;  // K/V LDS row stride (144 B, rows 16B-aligned)

// Longest-first task table (48 tasks/bh): TQT = q-tile, TMODE: 0 = seg0
// (chunks [0, c0-1], no diag), 1 = seg1 (chunks [c0, qt], diag), 2 = full.
// c0 = ceil((qt+1)/2) = (qt+2)>>1.  Lengths descend 16..1.
__device__ const unsigned char TQT[48] = {
    31,31,30,15,  30,29,29,28,14,  28,27,27,26,13,  26,25,25,24,12,
    24,23,23,22,11,  22,21,21,20,10,  20,19,19,18,9,  18,17,17,16,8,
    16,7,  6,5,4,3,2,1,0};
__device__ const unsigned char TMODE[48] = {
    0,1,0,2,  1,0,1,0,2,  1,0,1,0,2,  1,0,1,0,2,
    1,0,1,0,2,  1,0,1,0,2,  1,0,1,0,2,  1,0,1,0,2,
    1,2,  2,2,2,2,2,2,2};

DEV void attn_step(const bf16x8 fk[4][2], const bf16x8 fv[2][4],
                   const bf16x8* fq, f32x4* Oacc,
                   float& m_i, float& l_i, bool diag,
                   int wave, int quad, int l16) {
    // S^T: 4 key-tiles x 2 k-steps over d
    f32x4 st[4];
    #pragma unroll
    for (int nt = 0; nt < 4; ++nt) {
        f32x4 t = {};
        t = mfma16(fk[nt][0], fq[0], t);   // A=K (m=key), B=Q (n=q)
        t = mfma16(fk[nt][1], fq[1], t);
        st[nt] = t;
    }

    // causal mask on diagonal tile: key_loc <= q_loc
    if (diag) {
        const int qg = wave * 16 + l16;
        #pragma unroll
        for (int nt = 0; nt < 4; ++nt)
            #pragma unroll
            for (int reg = 0; reg < 4; ++reg) {
                const int kg = nt * 16 + quad * 4 + reg;
                st[nt][reg] = (kg <= qg) ? st[nt][reg] : -INFINITY;
            }
    }

    // row max: depth-4 tree + 2 cross-quad shuffles (lane = quad*16+l16)
    float v[16];
    #pragma unroll
    for (int nt = 0; nt < 4; ++nt)
        #pragma unroll
        for (int reg = 0; reg < 4; ++reg)
            v[nt * 4 + reg] = st[nt][reg];
    #pragma unroll
    for (int s = 8; s > 0; s >>= 1)
        #pragma unroll
        for (int i = 0; i < s; ++i)
            v[i] = fmaxf(v[i], v[i + s]);
    float vmax = v[0];
    vmax = fmaxf(vmax, __shfl_xor(vmax, 16, 64));
    vmax = fmaxf(vmax, __shfl_xor(vmax, 32, 64));

    const float mnew = fmaxf(m_i, vmax);
    const float alpha = __builtin_amdgcn_exp2f(m_i - mnew);
    m_i = mnew;

    #pragma unroll
    for (int nt = 0; nt < 4; ++nt)
        #pragma unroll
        for (int reg = 0; reg < 4; ++reg) {
            const float p = __builtin_amdgcn_exp2f(st[nt][reg] - mnew);
            st[nt][reg] = p;
            v[nt * 4 + reg] = p;
        }
    #pragma unroll
    for (int s = 8; s > 0; s >>= 1)
        #pragma unroll
        for (int i = 0; i < s; ++i)
            v[i] += v[i + s];
    float vsum = v[0];
    vsum += __shfl_xor(vsum, 16, 64);
    vsum += __shfl_xor(vsum, 32, 64);
    l_i = l_i * alpha + vsum;

    #pragma unroll
    for (int dt = 0; dt < 4; ++dt)
        #pragma unroll
        for (int reg = 0; reg < 4; ++reg)
            Oacc[dt][reg] *= alpha;

    // P^T B-operand: reg j<4 = st[2p][j] (key p*32+quad*4+j),
    //                reg j>=4 = st[2p+1][j-4] (key p*32+16+quad*4+j-4)
    #pragma unroll
    for (int pair = 0; pair < 2; ++pair) {
        bf16x8 pb;
        #pragma unroll
        for (int j = 0; j < 4; ++j) {
            pb[j]     = (__bf16)st[2 * pair][j];
            pb[4 + j] = (__bf16)st[2 * pair + 1][j];
        }
        #pragma unroll
        for (int dt = 0; dt < 4; ++dt)
            Oacc[dt] = mfma16(fv[pair][dt], pb, Oacc[dt]);
    }
}

template <int SPLIT>
__global__ __launch_bounds__(256, 4)
void attn_kernel(const u16* __restrict__ Q, const u16* __restrict__ Kb,
                 const u16* __restrict__ Vt, u16* __restrict__ O,
                 float* __restrict__ Opart, float* __restrict__ MLpart) {
    __shared__ alignas(16) u16 Ks[2][64 * KST];
    __shared__ alignas(16) u16 Vs[2][64 * KST];

    const int bid = (int)blockIdx.x;
    int qt, mode, bh;
    if (SPLIT) {
        const int task = bid >> 5;
        qt = TQT[task]; mode = TMODE[task];
        bh = bid & 31;                       // bh%8 == bid%8 -> XCD locality
    } else {
        qt = 31 - (bid >> 5); mode = 2;
        bh = (bid & 7) + 8 * ((bid >> 3) & 3);
    }
    const int c0 = (qt + 2) >> 1;            // split point (ceil half)
    int j0 = 0, j1 = qt;
    bool hasdiag = true;
    if (SPLIT && mode == 0) { j1 = c0 - 1; hasdiag = false; }
    if (SPLIT && mode == 1) { j0 = c0; }

    const int tid = threadIdx.x;
    const int wave = tid >> 6, lane = tid & 63;
    const int quad = lane >> 4, l16 = lane & 15;

    const u16* Qh = Q  + (size_t)bh * TT * DH;
    const u16* Kh = Kb + (size_t)bh * TT * DH;
    const u16* Vh = Vt + (size_t)bh * DH * TT;

    const int row = qt * 64 + wave * 16;

    // Q fragments (B-operand: n = l16 = q, k = quad*8+j over d)
    bf16x8 fq[2];
    fq[0] = *(const bf16x8*)&Qh[(row + l16) * DH + quad * 8];
    fq[1] = *(const bf16x8*)&Qh[(row + l16) * DH + 32 + quad * 8];

    f32x4 Oa[4] = {};
    float m_i = -INFINITY, l_i = 0.f;

    // Chunk staging: thread i covers 16B at row (i>>3), col (i&7)*8, +row32.
    const int trow = tid >> 3;
    const int ic   = tid & 7;            // 8-key group index
    const int tcol = ic * 8;
    // V pair-permuted destination column for this thread's 8 keys:
    //   keys 8*ic..8*ic+7 -> cols c1..c1+3 and c1+8..c1+11
    const int vc1 = 32 * (ic >> 2) + 16 * (ic & 1) + 4 * ((ic & 3) >> 1);
    uint4 kr0, kr1, vr0, vr1;

    auto load_chunk = [&](int j) {
        const u16* ks = Kh + (size_t)j * 64 * DH;
        kr0 = *(const uint4*)&ks[trow * DH + tcol];
        kr1 = *(const uint4*)&ks[(trow + 32) * DH + tcol];
        const u16* vs = Vh + (size_t)j * 64;
        vr0 = *(const uint4*)&vs[(size_t)trow * TT + tcol];
        vr1 = *(const uint4*)&vs[(size_t)(trow + 32) * TT + tcol];
    };
    auto write_chunk = [&](int buf) {
        *(uint4*)&Ks[buf][trow * KST + tcol]        = kr0;
        *(uint4*)&Ks[buf][(trow + 32) * KST + tcol] = kr1;
        // V: split each 16B into two 8B halves at permuted columns
        *(uint2*)&Vs[buf][trow * KST + vc1]            = *(const uint2*)&vr0;
        *(uint2*)&Vs[buf][trow * KST + vc1 + 8]        = *((const uint2*)&vr0 + 1);
        *(uint2*)&Vs[buf][(trow + 32) * KST + vc1]     = *(const uint2*)&vr1;
        *(uint2*)&Vs[buf][(trow + 32) * KST + vc1 + 8] = *((const uint2*)&vr1 + 1);
    };

    load_chunk(j0);
    write_chunk(0);

    for (int j = j0; j <= j1; ++j) {
        const int cur = (j - j0) & 1;
        __syncthreads();                    // buf[cur] staged & visible
        if (j < j1) load_chunk(j + 1);      // loads fly during compute

        // Hoist K/V fragments (issued early; compiler inserts lgkm waits)
        bf16x8 fk[4][2], fv[2][4];
        #pragma unroll
        for (int nt = 0; nt < 4; ++nt) {
            fk[nt][0] = *(const bf16x8*)&Ks[cur][(nt * 16 + l16) * KST + quad * 8];
            fk[nt][1] = *(const bf16x8*)&Ks[cur][(nt * 16 + l16) * KST + 32 + quad * 8];
        }
        #pragma unroll
        for (int pair = 0; pair < 2; ++pair)
            #pragma unroll
            for (int dt = 0; dt < 4; ++dt)
                fv[pair][dt] = *(const bf16x8*)
                    &Vs[cur][(dt * 16 + l16) * KST + pair * 32 + quad * 8];

        attn_step(fk, fv, fq, Oa, m_i, l_i, hasdiag && (j == qt),
                  wave, quad, l16);
        if (j < j1) write_chunk(cur ^ 1);   // after all buf[cur^1] readers done
    }

    if (!SPLIT || mode == 2) {
        // Direct epilogue: O^T rows d = dt*16+quad*4+reg, col q = l16.
        const int b = bh >> 4, h = bh & 15;
        const float r_i = 1.f / l_i;
        #pragma unroll
        for (int dt = 0; dt < 4; ++dt) {
            u16 oa[4];
            #pragma unroll
            for (int reg = 0; reg < 4; ++reg)
                oa[reg] = f2bf(Oa[dt][reg] * r_i);
            *(uint2*)&O[((size_t)(b * TT + row + l16)) * CD + h * DH + dt * 16 + quad * 4] =
                *(const uint2*)oa;
        }
    } else {
        // Partial epilogue: Opart[pidx][d=64][qrow=64] f32; ML[pidx][m64|l64].
        const int pidx = ((qt - 16) * 32 + bh) * 2 + mode;
        float* Op = Opart + (size_t)pidx * 4096;
        #pragma unroll
        for (int dt = 0; dt < 4; ++dt)
            #pragma unroll
            for (int reg = 0; reg < 4; ++reg)
                Op[(dt * 16 + quad * 4 + reg) * 64 + wave * 16 + l16] = Oa[dt][reg];
        if (quad == 0) {                     // m,l uniform across quads
            MLpart[pidx * 128 + wave * 16 + l16]      = m_i;
            MLpart[pidx * 128 + 64 + wave * 16 + l16] = l_i;
        }
    }
}

// Merge the two partials of each split tile (qt>=16): standard online-
// softmax merge.  Grid 512 = 16 qt x 32 bh; 256 thr: row = tid>>2 (0..63),
// 16 d-values per thread (contiguous 32B store).
__global__ __launch_bounds__(256)
void attn_combine(const float* __restrict__ Opart,
                  const float* __restrict__ MLpart, u16* __restrict__ O) {
    const int pair = (int)blockIdx.x;
    const int qti = pair >> 5, bh = pair & 31;
    const int qt = 16 + qti;
    const int pbase = (qti * 32 + bh) * 2;
    const float* O0 = Opart + (size_t)pbase * 4096;
    const float* O1 = O0 + 4096;
    const float* ml0 = MLpart + pbase * 128;
    const float* ml1 = ml0 + 128;

    const int tid = threadIdx.x;
    const int rrow = tid >> 2;              // q-row 0..63
    const int d0 = (tid & 3) * 16;

    const float m0 = ml0[rrow], l0 = ml0[64 + rrow];
    const float m1 = ml1[rrow], l1 = ml1[64 + rrow];
    const float M = fmaxf(m0, m1);
    const float w0 = __builtin_amdgcn_exp2f(m0 - M);
    const float w1 = __builtin_amdgcn_exp2f(m1 - M);
    const float rL = 1.f / (l0 * w0 + l1 * w1);

    u16 o[16];
    #pragma unroll
    for (int i = 0; i < 16; ++i) {
        const int d = d0 + i;
        o[i] = f2bf((O0[d * 64 + rrow] * w0 + O1[d * 64 + rrow] * w1) * rL);
    }
    const int b = bh >> 4, h = bh & 15;
    u16* dst = &O[((size_t)(b * TT + qt * 64 + rrow)) * CD + h * DH + d0];
    *(uint4*)dst = *(const uint4*)o;
    *(uint4*)(dst + 8) = *((const uint4*)o + 1);
}

// ---------------------------------------------------------------------------
extern "C" void kernel_launch(void* const* d_in, const int* in_sizes, int n_in,
                              void* d_out, int out_size, void* d_ws, size_t ws_size,
                              hipStream_t stream) {
    (void)in_sizes; (void)n_in; (void)out_size;
    const float* x    = (const float*)d_in[0];   // (4096, 1024) fp32
    const float* Wqkv = (const float*)d_in[1];   // (1024, 3072) fp32
    const float* Wo   = (const float*)d_in[2];   // (1024, 1024) fp32
    float* out = (float*)d_out;                  // (4096, 1024) fp32

    char* ws = (char*)d_ws;
    u16* xb    = (u16*)(ws + 0);                    // 4096x1024  (8 MB)
    u16* WqkvT = (u16*)(ws + (8u  << 20));          // 3072x1024  (6 MB)
    u16* WoT   = (u16*)(ws + (14u << 20));          // 1024x1024  (2 MB)
    u16* Qb    = (u16*)(ws + (16u << 20));          // (B,H,T,64) (8 MB)
    u16* Kb    = (u16*)(ws + (24u << 20));          // (B,H,T,64) (8 MB)
    u16* Vt    = (u16*)(ws + (32u << 20));          // (B,H,64,T) (8 MB)
    u16* attn  = (u16*)(ws + (40u << 20));          // (B,T,C)    (8 MB)
    float* Opart  = (float*)(ws + (48u << 20));     // 1024x4096 f32 (16.8 MB)
    float* MLpart = (float*)(ws + (65u << 20));     // 1024x128 f32  (0.5 MB)

    prep_kernel<<<6144, 256, 0, stream>>>(x, xb, Wqkv, WqkvT, Wo, WoT);

    // qkv = x @ W_qkv (3-deep pipelined, 128x128): grid 768 = 3 blocks/CU.
    gemm_db<1, 128, 24><<<768, 256, 0, stream>>>(
        xb, WqkvT, Qb, Kb, Vt, nullptr, BT, 3072, CD);

    if (ws_size >= (66u << 20)) {
        // KV-split attn: 1536 tasks (longest 16 steps) + combine of 512 pairs.
        attn_kernel<1><<<1536, 256, 0, stream>>>(Qb, Kb, Vt, attn, Opart, MLpart);
        attn_combine<<<512, 256, 0, stream>>>(Opart, MLpart, attn);
    } else {
        // Fallback: plain v5 (1024 single-q-tile blocks, longest-first).
        attn_kernel<0><<<1024, 256, 0, stream>>>(Qb, Kb, Vt, attn, nullptr, nullptr);
    }

    // out = attn @ W_o (3-deep pipelined, 128x64): grid 512 = 2 blocks/CU.
    gemm_db<0, 64, 16><<<512, 256, 0, stream>>>(
        attn, WoT, nullptr, nullptr, nullptr, out, BT, CD, CD);
}

// Round 8
// 175.487 us; speedup vs baseline: 1.0343x; 1.0343x over previous
//
#include <hip/hip_runtime.h>

typedef unsigned short u16;
typedef unsigned int u32;
typedef __bf16 bf16x8 __attribute__((ext_vector_type(8)));
typedef float f32x4 __attribute__((ext_vector_type(4)));

#define DEV __device__ __forceinline__

// Problem constants (B,T,D_MODEL,H) = (2,2048,1024,16)
constexpr int BB = 2;
constexpr int TT = 2048;
constexpr int CD = 1024;
constexpr int HH = 16;
constexpr int DH = 64;
constexpr int BT = BB * TT;   // 4096

// softmax scale 1/8 folded with log2(e): S' = S/8*log2e, exp(x)=exp2(x')
#define QSCALE 0.18033688011112042f

// Native bf16 convert (RTNE): compiler packs pairs into v_cvt_pk_bf16_f32.
DEV u16 f2bf(float f) {
    return __builtin_bit_cast(u16, (__bf16)f);
}

DEV f32x4 mfma16(bf16x8 a, bf16x8 b, f32x4 c) {
    return __builtin_amdgcn_mfma_f32_16x16x32_bf16(a, b, c, 0, 0, 0);
}

// Async global->LDS, 16B per lane: LDS dest = wave-uniform base + lane*16.
DEV void gld_lds16(u16* lds, const u16* g) {
    __builtin_amdgcn_global_load_lds(
        (const __attribute__((address_space(1))) unsigned int*)g,
        (__attribute__((address_space(3))) unsigned int*)lds, 16, 0, 0);
}

// ---------------------------------------------------------------------------
// Fused preprocessing (single launch):
//   blocks [0,2048):      x fp32 -> bf16           (4096x1024)
//   blocks [2048,5120):   W_qkv (1024x3072) -> transposed bf16 (3072x1024)
//   blocks [5120,6144):   W_o   (1024x1024) -> transposed bf16 (1024x1024)
// ---------------------------------------------------------------------------
__global__ __launch_bounds__(256)
void prep_kernel(const float* __restrict__ x, u16* __restrict__ xb,
                 const float* __restrict__ Wqkv, u16* __restrict__ WqkvT,
                 const float* __restrict__ Wo, u16* __restrict__ WoT) {
    const int tid = threadIdx.x;
    int blk = blockIdx.x;
    if (blk < 2048) {                       // convert job
        const int i = (blk * 256 + tid) * 8;
        float4 a = *(const float4*)&x[i];
        float4 b = *(const float4*)&x[i + 4];
        u16 t[8];
        t[0] = f2bf(a.x); t[1] = f2bf(a.y); t[2] = f2bf(a.z); t[3] = f2bf(a.w);
        t[4] = f2bf(b.x); t[5] = f2bf(b.y); t[6] = f2bf(b.z); t[7] = f2bf(b.w);
        *(uint4*)&xb[i] = *(const uint4*)t;
        return;                             // whole block exits (no barrier)
    }
    __shared__ u16 tile[32][33];
    const float* in; u16* out; int rows, cols, bx, by;
    if (blk < 5120) { blk -= 2048; in = Wqkv; out = WqkvT; rows = 1024; cols = 3072; bx = blk % 96; by = blk / 96; }
    else            { blk -= 5120; in = Wo;   out = WoT;   rows = 1024; cols = 1024; bx = blk % 32; by = blk / 32; }
    const int c0 = bx * 32, r0 = by * 32;
    const int tx = tid & 31, ty = tid >> 5;
    #pragma unroll
    for (int i = ty; i < 32; i += 8)
        tile[i][tx] = f2bf(in[(r0 + i) * cols + (c0 + tx)]);
    __syncthreads();
    #pragma unroll
    for (int i = ty; i < 32; i += 8)
        out[(c0 + i) * rows + (r0 + tx)] = tile[tx][i];
}

// ---------------------------------------------------------------------------
// GEMM v3: 3-deep pipelined staging + counted vmcnt (T4) + chunk-XOR LDS
// swizzle (T2).  C[M][N] = A[M][K] * Bt[N][K]^T, bf16->fp32 acc.
// BM=128, BN template (128 or 64), BK=32.  (Unchanged: conflicts measured 0;
// timing at the 2-phase-class structural plateau.)
// ---------------------------------------------------------------------------
template <int EPI, int BN, int GX>
__global__ __launch_bounds__(256)
void gemm_db(const u16* __restrict__ A, const u16* __restrict__ Bt,
             u16* __restrict__ out0, u16* __restrict__ out1,
             u16* __restrict__ out2, float* __restrict__ outf,
             int M, int N, int K) {
    constexpr int BM = 128, BK = 32, AST = 32;
    constexpr int NT = BN / 32;             // n-tiles per wave
    constexpr int NBLK = GX * 32;           // M/BM = 32 always here
    constexpr int CPX = NBLK / 8;           // blocks per XCD chunk
    __shared__ alignas(16) u16 As[3][BM * AST];
    __shared__ alignas(16) u16 Bs[3][BN * AST];

    const int tid  = threadIdx.x;
    const int wave = tid >> 6, lane = tid & 63;
    const int quad = lane >> 4, l16 = lane & 15;
    const int wm = (wave & 1) * 64, wn = (wave >> 1) * (BN / 2);

    // T1: XCD-aware chunked swizzle (bijective since NBLK % 8 == 0)
    int bid = (int)blockIdx.x;
    bid = (bid & 7) * CPX + (bid >> 3);
    const int bx = bid % GX, by = bid / GX;
    const int m0 = by * BM, n0 = bx * BN;

    // DMA staging: one instr = 64 lanes x 16B = 16 rows x 64B.
    // T2 pre-swizzled global source chunk.
    const int srowA = wave * 32 + (lane >> 2);
    const int srowB = wave * (BN / 4) + (lane >> 2);
    const int scol  = (((lane & 3) ^ ((lane >> 3) & 3))) * 8;
    const u16* ga0 = A  + (size_t)(m0 + srowA) * K + scol;
    const u16* ga1 = ga0 + (size_t)16 * K;
    const u16* gb0 = Bt + (size_t)(n0 + srowB) * K + scol;
    const u16* gb1 = gb0 + (size_t)16 * K;

    auto stage = [&](int buf, int k0) {
        gld_lds16(&As[buf][wave * 1024],           ga0 + k0);
        gld_lds16(&As[buf][wave * 1024 + 512],     ga1 + k0);
        gld_lds16(&Bs[buf][wave * (BN * 8)],       gb0 + k0);
        if constexpr (BN == 128)
            gld_lds16(&Bs[buf][wave * (BN * 8) + 512], gb1 + k0);
    };
    // mid-loop counted wait: one stage (LPS loads) stays in flight
    auto wait_lps = [&]() {
        if constexpr (BN == 128) asm volatile("s_waitcnt vmcnt(4)" ::: "memory");
        else                     asm volatile("s_waitcnt vmcnt(3)" ::: "memory");
    };

    f32x4 acc[4][NT] = {};

    stage(0, 0);
    stage(1, BK);
    wait_lps();                              // step-0 buffers landed
    __builtin_amdgcn_s_barrier();

    const int sx = ((l16 >> 1) & 3) * 8;     // T2 read-side XOR term
    const int NS = K / BK;
    int cb = 0;                              // current buffer
    for (int t = 0; t < NS; ++t) {
        const bool pf = (t + 2 < NS);
        int sb = cb + 2; if (sb >= 3) sb -= 3;
        if (pf) stage(sb, (t + 2) * BK);

        bf16x8 fa[4], fb[NT];
        #pragma unroll
        for (int mt = 0; mt < 4; ++mt)
            fa[mt] = *(const bf16x8*)
                &As[cb][(wm + mt * 16 + l16) * AST + (quad * 8 ^ sx)];
        #pragma unroll
        for (int nt = 0; nt < NT; ++nt)
            fb[nt] = *(const bf16x8*)
                &Bs[cb][(wn + nt * 16 + l16) * AST + (quad * 8 ^ sx)];
        #pragma unroll
        for (int mt = 0; mt < 4; ++mt)
            #pragma unroll
            for (int nt = 0; nt < NT; ++nt)
                acc[mt][nt] = mfma16(fa[mt], fb[nt], acc[mt][nt]);

        if (pf) wait_lps();                  // drain stage for step t+1 only
        else    asm volatile("s_waitcnt vmcnt(0)" ::: "memory");
        __builtin_amdgcn_s_barrier();
        cb = (cb + 1 == 3) ? 0 : cb + 1;
    }

    // Epilogue. C/D layout: row = quad*4+reg, col = l16.
    #pragma unroll
    for (int mt = 0; mt < 4; ++mt) {
        #pragma unroll
        for (int nt = 0; nt < NT; ++nt) {
            #pragma unroll
            for (int reg = 0; reg < 4; ++reg) {
                const int r = m0 + wm + mt * 16 + quad * 4 + reg;
                const int c = n0 + wn + nt * 16 + l16;
                if (EPI == 0) {
                    outf[(size_t)r * N + c] = acc[mt][nt][reg];
                } else {
                    const int which = c >> 10;       // 0=q 1=k 2=v
                    const int cc = c & 1023;
                    const int h = cc >> 6, d = cc & 63;
                    const int b = r >> 11, t = r & 2047;
                    const int bh = b * HH + h;
                    if (which == 0) {
                        out0[((size_t)bh * TT + t) * DH + d] =
                            f2bf(acc[mt][nt][reg] * QSCALE);
                    } else if (which == 1) {
                        out1[((size_t)bh * TT + t) * DH + d] = f2bf(acc[mt][nt][reg]);
                    } else {
                        out2[((size_t)bh * DH + d) * TT + t] = f2bf(acc[mt][nt][reg]);
                    }
                }
            }
        }
    }
}

// ---------------------------------------------------------------------------
// Flash attention v8 (causal): v5 schedule (1024 single-q-tile blocks,
// longest-first, bh->XCD locality) + per-step VALU cuts:
//  (a) ONES-ROW l-ACCUMULATION: a constant A-fragment (lanes l16==0 hold
//      1.0) makes one extra MFMA per pair compute sum(P) into lacc --
//      replaces the per-step 15-add sum tree + 2 cross-quad shuffles.
//      l is read back with a single shuffle in the epilogue, and is
//      consistent with the bf16-P numerator (both sum converted P).
//  (b) DEFER-MAX (T13, THR=8, exp2 domain): skip alpha-exp2 + O/l rescale
//      when __all(vmax - m_i <= 8); P bounded by 2^8=256 (bf16/f32 safe).
//      Wave-uniform branch; m_i = -inf forces the rescale path on step 0.
// Rationale: three scheduling variants (v5/v6/v7-split) all ~41-43 us ->
// bound is per-step softmax VALU x 16896 steps, not parallelism.
// ---------------------------------------------------------------------------
constexpr int KST = 72;  // K/V LDS row stride (144 B, rows 16B-aligned)

DEV void attn_step(const bf16x8 fk[4][2], const bf16x8 fv[2][4],
                   const bf16x8 fone, const bf16x8* fq,
                   f32x4* Oacc, f32x4& lacc, float& m_i, bool diag,
                   int wave, int quad, int l16) {
    // S^T: 4 key-tiles x 2 k-steps over d
    f32x4 st[4];
    #pragma unroll
    for (int nt = 0; nt < 4; ++nt) {
        f32x4 t = {};
        t = mfma16(fk[nt][0], fq[0], t);   // A=K (m=key), B=Q (n=q)
        t = mfma16(fk[nt][1], fq[1], t);
        st[nt] = t;
    }

    // causal mask on diagonal tile: key_loc <= q_loc
    if (diag) {
        const int qg = wave * 16 + l16;
        #pragma unroll
        for (int nt = 0; nt < 4; ++nt)
            #pragma unroll
            for (int reg = 0; reg < 4; ++reg) {
                const int kg = nt * 16 + quad * 4 + reg;
                st[nt][reg] = (kg <= qg) ? st[nt][reg] : -INFINITY;
            }
    }

    // row max: depth-4 tree + 2 cross-quad shuffles (lane = quad*16+l16)
    float v[16];
    #pragma unroll
    for (int nt = 0; nt < 4; ++nt)
        #pragma unroll
        for (int reg = 0; reg < 4; ++reg)
            v[nt * 4 + reg] = st[nt][reg];
    #pragma unroll
    for (int s = 8; s > 0; s >>= 1)
        #pragma unroll
        for (int i = 0; i < s; ++i)
            v[i] = fmaxf(v[i], v[i + s]);
    float vmax = v[0];
    vmax = fmaxf(vmax, __shfl_xor(vmax, 16, 64));
    vmax = fmaxf(vmax, __shfl_xor(vmax, 32, 64));

    // defer-max: rescale only when some row's max grew past THR=8 (exp2 dom)
    if (!__all(vmax - m_i <= 8.f)) {
        const float mnew = fmaxf(m_i, vmax);
        const float alpha = __builtin_amdgcn_exp2f(m_i - mnew);
        m_i = mnew;
        #pragma unroll
        for (int dt = 0; dt < 4; ++dt)
            #pragma unroll
            for (int reg = 0; reg < 4; ++reg)
                Oacc[dt][reg] *= alpha;
        #pragma unroll
        for (int reg = 0; reg < 4; ++reg)
            lacc[reg] *= alpha;
    }

    #pragma unroll
    for (int nt = 0; nt < 4; ++nt)
        #pragma unroll
        for (int reg = 0; reg < 4; ++reg)
            st[nt][reg] = __builtin_amdgcn_exp2f(st[nt][reg] - m_i);

    // P^T B-operand: reg j<4 = st[2p][j] (key p*32+quad*4+j),
    //                reg j>=4 = st[2p+1][j-4] (key p*32+16+quad*4+j-4)
    // ones-row MFMA accumulates sum(P) into lacc (C row 0 = quad0/reg0).
    #pragma unroll
    for (int pair = 0; pair < 2; ++pair) {
        bf16x8 pb;
        #pragma unroll
        for (int j = 0; j < 4; ++j) {
            pb[j]     = (__bf16)st[2 * pair][j];
            pb[4 + j] = (__bf16)st[2 * pair + 1][j];
        }
        lacc = mfma16(fone, pb, lacc);
        #pragma unroll
        for (int dt = 0; dt < 4; ++dt)
            Oacc[dt] = mfma16(fv[pair][dt], pb, Oacc[dt]);
    }
}

__global__ __launch_bounds__(256, 4)
void attn_kernel(const u16* __restrict__ Q, const u16* __restrict__ Kb,
                 const u16* __restrict__ Vt, u16* __restrict__ O) {
    __shared__ alignas(16) u16 Ks[2][64 * KST];
    __shared__ alignas(16) u16 Vs[2][64 * KST];

    // Decode: bid[2:0]=xcd (hosts bh with bh&7==xcd), bid[4:3]=bh>>3,
    // bid[9:5]=31-qt (longest q-tile dispatched first).
    const int bid = (int)blockIdx.x;
    const int j2 = bid >> 3;
    const int qt = 31 - (j2 >> 2);
    const int bh = (bid & 7) + 8 * (j2 & 3);
    const int jmax = qt;

    const int tid = threadIdx.x;
    const int wave = tid >> 6, lane = tid & 63;
    const int quad = lane >> 4, l16 = lane & 15;

    const u16* Qh = Q  + (size_t)bh * TT * DH;
    const u16* Kh = Kb + (size_t)bh * TT * DH;
    const u16* Vh = Vt + (size_t)bh * DH * TT;

    const int row = qt * 64 + wave * 16;

    // Q fragments (B-operand: n = l16 = q, k = quad*8+j over d)
    bf16x8 fq[2];
    fq[0] = *(const bf16x8*)&Qh[(row + l16) * DH + quad * 8];
    fq[1] = *(const bf16x8*)&Qh[(row + l16) * DH + 32 + quad * 8];

    // ones A-fragment: row (m) index = l16, so lanes with l16==0 hold the
    // all-ones row 0; C row 0 = quad0/reg0 collects sum(P) per q-col.
    bf16x8 fone;
    {
        const __bf16 ov = (l16 == 0) ? (__bf16)1.f : (__bf16)0.f;
        #pragma unroll
        for (int j = 0; j < 8; ++j) fone[j] = ov;
    }

    f32x4 Oa[4] = {}, lacc = {};
    float m_i = -INFINITY;

    // Chunk staging: thread i covers 16B at row (i>>3), col (i&7)*8, +row32.
    const int trow = tid >> 3;
    const int ic   = tid & 7;            // 8-key group index
    const int tcol = ic * 8;
    // V pair-permuted destination column for this thread's 8 keys:
    //   keys 8*ic..8*ic+7 -> cols c1..c1+3 and c1+8..c1+11
    const int vc1 = 32 * (ic >> 2) + 16 * (ic & 1) + 4 * ((ic & 3) >> 1);
    uint4 kr0, kr1, vr0, vr1;

    auto load_chunk = [&](int j) {
        const u16* ks = Kh + (size_t)j * 64 * DH;
        kr0 = *(const uint4*)&ks[trow * DH + tcol];
        kr1 = *(const uint4*)&ks[(trow + 32) * DH + tcol];
        const u16* vs = Vh + (size_t)j * 64;
        vr0 = *(const uint4*)&vs[(size_t)trow * TT + tcol];
        vr1 = *(const uint4*)&vs[(size_t)(trow + 32) * TT + tcol];
    };
    auto write_chunk = [&](int buf) {
        *(uint4*)&Ks[buf][trow * KST + tcol]        = kr0;
        *(uint4*)&Ks[buf][(trow + 32) * KST + tcol] = kr1;
        // V: split each 16B into two 8B halves at permuted columns
        *(uint2*)&Vs[buf][trow * KST + vc1]            = *(const uint2*)&vr0;
        *(uint2*)&Vs[buf][trow * KST + vc1 + 8]        = *((const uint2*)&vr0 + 1);
        *(uint2*)&Vs[buf][(trow + 32) * KST + vc1]     = *(const uint2*)&vr1;
        *(uint2*)&Vs[buf][(trow + 32) * KST + vc1 + 8] = *((const uint2*)&vr1 + 1);
    };

    load_chunk(0);
    write_chunk(0);

    for (int j = 0; j <= jmax; ++j) {
        const int cur = j & 1;
        __syncthreads();                    // buf[cur] staged & visible
        if (j < jmax) load_chunk(j + 1);    // loads fly during compute

        // Hoist K/V fragments (issued early; compiler inserts lgkm waits)
        bf16x8 fk[4][2], fv[2][4];
        #pragma unroll
        for (int nt = 0; nt < 4; ++nt) {
            fk[nt][0] = *(const bf16x8*)&Ks[cur][(nt * 16 + l16) * KST + quad * 8];
            fk[nt][1] = *(const bf16x8*)&Ks[cur][(nt * 16 + l16) * KST + 32 + quad * 8];
        }
        #pragma unroll
        for (int pair = 0; pair < 2; ++pair)
            #pragma unroll
            for (int dt = 0; dt < 4; ++dt)
                fv[pair][dt] = *(const bf16x8*)
                    &Vs[cur][(dt * 16 + l16) * KST + pair * 32 + quad * 8];

        attn_step(fk, fv, fone, fq, Oa, lacc, m_i, (j == qt),
                  wave, quad, l16);
        if (j < jmax) write_chunk(cur ^ 1); // after all buf[cur^1] readers done
    }

    // l for this lane's q-col lives in the quad-0 lane of the same column.
    const float lrow = __shfl(lacc[0], l16, 64);
    const float r_i = 1.f / lrow;

    // Epilogue: O^T rows d = dt*16+quad*4+reg, col q = l16; write (B,T,C).
    const int b = bh >> 4, h = bh & 15;
    #pragma unroll
    for (int dt = 0; dt < 4; ++dt) {
        u16 oa[4];
        #pragma unroll
        for (int reg = 0; reg < 4; ++reg)
            oa[reg] = f2bf(Oa[dt][reg] * r_i);
        *(uint2*)&O[((size_t)(b * TT + row + l16)) * CD + h * DH + dt * 16 + quad * 4] =
            *(const uint2*)oa;
    }
}

// ---------------------------------------------------------------------------
extern "C" void kernel_launch(void* const* d_in, const int* in_sizes, int n_in,
                              void* d_out, int out_size, void* d_ws, size_t ws_size,
                              hipStream_t stream) {
    (void)in_sizes; (void)n_in; (void)out_size; (void)ws_size;
    const float* x    = (const float*)d_in[0];   // (4096, 1024) fp32
    const float* Wqkv = (const float*)d_in[1];   // (1024, 3072) fp32
    const float* Wo   = (const float*)d_in[2];   // (1024, 1024) fp32
    float* out = (float*)d_out;                  // (4096, 1024) fp32

    char* ws = (char*)d_ws;
    u16* xb    = (u16*)(ws + 0);                    // 4096x1024  (8 MB)
    u16* WqkvT = (u16*)(ws + (8u  << 20));          // 3072x1024  (6 MB)
    u16* WoT   = (u16*)(ws + (14u << 20));          // 1024x1024  (2 MB)
    u16* Qb    = (u16*)(ws + (16u << 20));          // (B,H,T,64) (8 MB)
    u16* Kb    = (u16*)(ws + (24u << 20));          // (B,H,T,64) (8 MB)
    u16* Vt    = (u16*)(ws + (32u << 20));          // (B,H,64,T) (8 MB)
    u16* attn  = (u16*)(ws + (40u << 20));          // (B,T,C)    (8 MB)

    prep_kernel<<<6144, 256, 0, stream>>>(x, xb, Wqkv, WqkvT, Wo, WoT);

    // qkv = x @ W_qkv (3-deep pipelined, 128x128): grid 768 = 3 blocks/CU.
    gemm_db<1, 128, 24><<<768, 256, 0, stream>>>(
        xb, WqkvT, Qb, Kb, Vt, nullptr, BT, 3072, CD);

    // attn: 1024 single-q-tile blocks, longest-first, bh->XCD locality.
    attn_kernel<<<1024, 256, 0, stream>>>(Qb, Kb, Vt, attn);

    // out = attn @ W_o (3-deep pipelined, 128x64): grid 512 = 2 blocks/CU.
    gemm_db<0, 64, 16><<<512, 256, 0, stream>>>(
        attn, WoT, nullptr, nullptr, nullptr, out, BT, CD, CD);
}

// Round 9
// 174.476 us; speedup vs baseline: 1.0403x; 1.0058x over previous
//
#include <hip/hip_runtime.h>

typedef unsigned short u16;
typedef unsigned int u32;
typedef __bf16 bf16x8 __attribute__((ext_vector_type(8)));
typedef float f32x4 __attribute__((ext_vector_type(4)));

#define DEV __device__ __forceinline__

// Problem constants (B,T,D_MODEL,H) = (2,2048,1024,16)
constexpr int BB = 2;
constexpr int TT = 2048;
constexpr int CD = 1024;
constexpr int HH = 16;
constexpr int DH = 64;
constexpr int BT = BB * TT;   // 4096

// softmax scale 1/8 folded with log2(e): S' = S/8*log2e, exp(x)=exp2(x')
#define QSCALE 0.18033688011112042f

// Native bf16 convert (RTNE): compiler packs pairs into v_cvt_pk_bf16_f32.
DEV u16 f2bf(float f) {
    return __builtin_bit_cast(u16, (__bf16)f);
}

DEV f32x4 mfma16(bf16x8 a, bf16x8 b, f32x4 c) {
    return __builtin_amdgcn_mfma_f32_16x16x32_bf16(a, b, c, 0, 0, 0);
}

// Async global->LDS, 16B per lane: LDS dest = wave-uniform base + lane*16.
DEV void gld_lds16(u16* lds, const u16* g) {
    __builtin_amdgcn_global_load_lds(
        (const __attribute__((address_space(1))) unsigned int*)g,
        (__attribute__((address_space(3))) unsigned int*)lds, 16, 0, 0);
}

// ---------------------------------------------------------------------------
// Fused preprocessing (single launch):
//   blocks [0,2048):      x fp32 -> bf16           (4096x1024)
//   blocks [2048,5120):   W_qkv (1024x3072) -> transposed bf16 (3072x1024)
//   blocks [5120,6144):   W_o   (1024x1024) -> transposed bf16 (1024x1024)
// ---------------------------------------------------------------------------
__global__ __launch_bounds__(256)
void prep_kernel(const float* __restrict__ x, u16* __restrict__ xb,
                 const float* __restrict__ Wqkv, u16* __restrict__ WqkvT,
                 const float* __restrict__ Wo, u16* __restrict__ WoT) {
    const int tid = threadIdx.x;
    int blk = blockIdx.x;
    if (blk < 2048) {                       // convert job
        const int i = (blk * 256 + tid) * 8;
        float4 a = *(const float4*)&x[i];
        float4 b = *(const float4*)&x[i + 4];
        u16 t[8];
        t[0] = f2bf(a.x); t[1] = f2bf(a.y); t[2] = f2bf(a.z); t[3] = f2bf(a.w);
        t[4] = f2bf(b.x); t[5] = f2bf(b.y); t[6] = f2bf(b.z); t[7] = f2bf(b.w);
        *(uint4*)&xb[i] = *(const uint4*)t;
        return;                             // whole block exits (no barrier)
    }
    __shared__ u16 tile[32][33];
    const float* in; u16* out; int rows, cols, bx, by;
    if (blk < 5120) { blk -= 2048; in = Wqkv; out = WqkvT; rows = 1024; cols = 3072; bx = blk % 96; by = blk / 96; }
    else            { blk -= 5120; in = Wo;   out = WoT;   rows = 1024; cols = 1024; bx = blk % 32; by = blk / 32; }
    const int c0 = bx * 32, r0 = by * 32;
    const int tx = tid & 31, ty = tid >> 5;
    #pragma unroll
    for (int i = ty; i < 32; i += 8)
        tile[i][tx] = f2bf(in[(r0 + i) * cols + (c0 + tx)]);
    __syncthreads();
    #pragma unroll
    for (int i = ty; i < 32; i += 8)
        out[(c0 + i) * rows + (r0 + tx)] = tile[tx][i];
}

// ---------------------------------------------------------------------------
// GEMM v4: 3-deep pipelined staging + counted vmcnt (T4) + chunk-XOR LDS
// swizzle (T2).  C[M][N] = A[M][K] * Bt[N][K]^T, bf16->fp32 acc.
// Template BM/BN (tiles): QKV = 128x128 (768 blocks, 3/CU); out-proj =
// 64x64 (1024 blocks, 4/CU).  Rationale for 64x64 out-proj: at 128x64 the
// per-step stage->vmcnt->barrier convoy dominated (29% LDS-port util,
// 193 TF); smaller tile + 4 blocks/CU doubles cross-block TLP where the
// chain was the binding resource.  Per-XCD working set after the chunked
// swizzle: A-slice 1 MB + full WoT 2 MB = 3 MB < 4 MB XCD L2.
// T1 XCD-chunked block swizzle (grid % 8 == 0, bijective).
// EPI==0: fp32 store to outf.  EPI==1: QKV scatter (bf16 Q,K,V^T).
// ---------------------------------------------------------------------------
template <int EPI, int BM, int BN, int GX>
__global__ __launch_bounds__(256)
void gemm_db(const u16* __restrict__ A, const u16* __restrict__ Bt,
             u16* __restrict__ out0, u16* __restrict__ out1,
             u16* __restrict__ out2, float* __restrict__ outf,
             int M, int N, int K) {
    constexpr int BK = 32, AST = 32;
    constexpr int MT = BM / 32;             // m-tiles per wave
    constexpr int NT = BN / 32;             // n-tiles per wave
    constexpr int MBLK = 4096 / BM;         // M = 4096 always here
    constexpr int NBLK = GX * MBLK;
    constexpr int CPX = NBLK / 8;           // blocks per XCD chunk
    constexpr int LPS = BM / 64 + BN / 64;  // gld_lds per stage per wave
    __shared__ alignas(16) u16 As[3][BM * AST];
    __shared__ alignas(16) u16 Bs[3][BN * AST];

    const int tid  = threadIdx.x;
    const int wave = tid >> 6, lane = tid & 63;
    const int quad = lane >> 4, l16 = lane & 15;
    const int wm = (wave & 1) * (BM / 2), wn = (wave >> 1) * (BN / 2);

    // T1: XCD-aware chunked swizzle (bijective since NBLK % 8 == 0)
    int bid = (int)blockIdx.x;
    bid = (bid & 7) * CPX + (bid >> 3);
    const int bx = bid % GX, by = bid / GX;
    const int m0 = by * BM, n0 = bx * BN;

    // DMA staging: one instr = 64 lanes x 16B = 16 rows x 64B.
    // T2 pre-swizzled global source chunk (stored[r][c]=logical[c^((r>>1)&3)]).
    const int srowA = wave * (BM / 4) + (lane >> 2);
    const int srowB = wave * (BN / 4) + (lane >> 2);
    const int scol  = (((lane & 3) ^ ((lane >> 3) & 3))) * 8;
    const u16* ga0 = A  + (size_t)(m0 + srowA) * K + scol;
    const u16* ga1 = ga0 + (size_t)16 * K;
    const u16* gb0 = Bt + (size_t)(n0 + srowB) * K + scol;
    const u16* gb1 = gb0 + (size_t)16 * K;

    auto stage = [&](int buf, int k0) {
        gld_lds16(&As[buf][wave * (BM / 4) * 32],       ga0 + k0);
        if constexpr (BM == 128)
            gld_lds16(&As[buf][wave * (BM / 4) * 32 + 512], ga1 + k0);
        gld_lds16(&Bs[buf][wave * (BN / 4) * 32],       gb0 + k0);
        if constexpr (BN == 128)
            gld_lds16(&Bs[buf][wave * (BN / 4) * 32 + 512], gb1 + k0);
    };
    // mid-loop counted wait: one stage (LPS loads) stays in flight
    auto wait_lps = [&]() {
        if constexpr (LPS == 4)      asm volatile("s_waitcnt vmcnt(4)" ::: "memory");
        else if constexpr (LPS == 3) asm volatile("s_waitcnt vmcnt(3)" ::: "memory");
        else                         asm volatile("s_waitcnt vmcnt(2)" ::: "memory");
    };

    f32x4 acc[MT][NT] = {};

    stage(0, 0);
    stage(1, BK);
    wait_lps();                              // step-0 buffers landed
    __builtin_amdgcn_s_barrier();

    const int sx = ((l16 >> 1) & 3) * 8;     // T2 read-side XOR term
    const int NS = K / BK;
    int cb = 0;                              // current buffer
    for (int t = 0; t < NS; ++t) {
        const bool pf = (t + 2 < NS);
        int sb = cb + 2; if (sb >= 3) sb -= 3;
        if (pf) stage(sb, (t + 2) * BK);

        bf16x8 fa[MT], fb[NT];
        #pragma unroll
        for (int mt = 0; mt < MT; ++mt)
            fa[mt] = *(const bf16x8*)
                &As[cb][(wm + mt * 16 + l16) * AST + (quad * 8 ^ sx)];
        #pragma unroll
        for (int nt = 0; nt < NT; ++nt)
            fb[nt] = *(const bf16x8*)
                &Bs[cb][(wn + nt * 16 + l16) * AST + (quad * 8 ^ sx)];
        #pragma unroll
        for (int mt = 0; mt < MT; ++mt)
            #pragma unroll
            for (int nt = 0; nt < NT; ++nt)
                acc[mt][nt] = mfma16(fa[mt], fb[nt], acc[mt][nt]);

        if (pf) wait_lps();                  // drain stage for step t+1 only
        else    asm volatile("s_waitcnt vmcnt(0)" ::: "memory");
        __builtin_amdgcn_s_barrier();
        cb = (cb + 1 == 3) ? 0 : cb + 1;
    }

    // Epilogue. C/D layout: row = quad*4+reg, col = l16.
    #pragma unroll
    for (int mt = 0; mt < MT; ++mt) {
        #pragma unroll
        for (int nt = 0; nt < NT; ++nt) {
            #pragma unroll
            for (int reg = 0; reg < 4; ++reg) {
                const int r = m0 + wm + mt * 16 + quad * 4 + reg;
                const int c = n0 + wn + nt * 16 + l16;
                if (EPI == 0) {
                    outf[(size_t)r * N + c] = acc[mt][nt][reg];
                } else {
                    const int which = c >> 10;       // 0=q 1=k 2=v
                    const int cc = c & 1023;
                    const int h = cc >> 6, d = cc & 63;
                    const int b = r >> 11, t = r & 2047;
                    const int bh = b * HH + h;
                    if (which == 0) {
                        out0[((size_t)bh * TT + t) * DH + d] =
                            f2bf(acc[mt][nt][reg] * QSCALE);
                    } else if (which == 1) {
                        out1[((size_t)bh * TT + t) * DH + d] = f2bf(acc[mt][nt][reg]);
                    } else {
                        out2[((size_t)bh * DH + d) * TT + t] = f2bf(acc[mt][nt][reg]);
                    }
                }
            }
        }
    }
}

// ---------------------------------------------------------------------------
// Flash attention v8 (causal): v5 schedule (1024 single-q-tile blocks,
// longest-first, bh->XCD locality) + per-step VALU cuts:
//  (a) ONES-ROW l-ACCUMULATION: a constant A-fragment (lanes l16==0 hold
//      1.0) makes one extra MFMA per pair compute sum(P) into lacc --
//      replaces the per-step 15-add sum tree + 2 cross-quad shuffles.
//  (b) DEFER-MAX (T13, THR=8, exp2 domain): skip alpha-exp2 + O/l rescale
//      when __all(vmax - m_i <= 8); P bounded by 2^8=256 (bf16/f32 safe).
// (Unchanged from round 8 -- measured win, isolating the GEMM change.)
// ---------------------------------------------------------------------------
constexpr int KST = 72;  // K/V LDS row stride (144 B, rows 16B-aligned)

DEV void attn_step(const bf16x8 fk[4][2], const bf16x8 fv[2][4],
                   const bf16x8 fone, const bf16x8* fq,
                   f32x4* Oacc, f32x4& lacc, float& m_i, bool diag,
                   int wave, int quad, int l16) {
    // S^T: 4 key-tiles x 2 k-steps over d
    f32x4 st[4];
    #pragma unroll
    for (int nt = 0; nt < 4; ++nt) {
        f32x4 t = {};
        t = mfma16(fk[nt][0], fq[0], t);   // A=K (m=key), B=Q (n=q)
        t = mfma16(fk[nt][1], fq[1], t);
        st[nt] = t;
    }

    // causal mask on diagonal tile: key_loc <= q_loc
    if (diag) {
        const int qg = wave * 16 + l16;
        #pragma unroll
        for (int nt = 0; nt < 4; ++nt)
            #pragma unroll
            for (int reg = 0; reg < 4; ++reg) {
                const int kg = nt * 16 + quad * 4 + reg;
                st[nt][reg] = (kg <= qg) ? st[nt][reg] : -INFINITY;
            }
    }

    // row max: depth-4 tree + 2 cross-quad shuffles (lane = quad*16+l16)
    float v[16];
    #pragma unroll
    for (int nt = 0; nt < 4; ++nt)
        #pragma unroll
        for (int reg = 0; reg < 4; ++reg)
            v[nt * 4 + reg] = st[nt][reg];
    #pragma unroll
    for (int s = 8; s > 0; s >>= 1)
        #pragma unroll
        for (int i = 0; i < s; ++i)
            v[i] = fmaxf(v[i], v[i + s]);
    float vmax = v[0];
    vmax = fmaxf(vmax, __shfl_xor(vmax, 16, 64));
    vmax = fmaxf(vmax, __shfl_xor(vmax, 32, 64));

    // defer-max: rescale only when some row's max grew past THR=8 (exp2 dom)
    if (!__all(vmax - m_i <= 8.f)) {
        const float mnew = fmaxf(m_i, vmax);
        const float alpha = __builtin_amdgcn_exp2f(m_i - mnew);
        m_i = mnew;
        #pragma unroll
        for (int dt = 0; dt < 4; ++dt)
            #pragma unroll
            for (int reg = 0; reg < 4; ++reg)
                Oacc[dt][reg] *= alpha;
        #pragma unroll
        for (int reg = 0; reg < 4; ++reg)
            lacc[reg] *= alpha;
    }

    #pragma unroll
    for (int nt = 0; nt < 4; ++nt)
        #pragma unroll
        for (int reg = 0; reg < 4; ++reg)
            st[nt][reg] = __builtin_amdgcn_exp2f(st[nt][reg] - m_i);

    // P^T B-operand: reg j<4 = st[2p][j] (key p*32+quad*4+j),
    //                reg j>=4 = st[2p+1][j-4] (key p*32+16+quad*4+j-4)
    // ones-row MFMA accumulates sum(P) into lacc (C row 0 = quad0/reg0).
    #pragma unroll
    for (int pair = 0; pair < 2; ++pair) {
        bf16x8 pb;
        #pragma unroll
        for (int j = 0; j < 4; ++j) {
            pb[j]     = (__bf16)st[2 * pair][j];
            pb[4 + j] = (__bf16)st[2 * pair + 1][j];
        }
        lacc = mfma16(fone, pb, lacc);
        #pragma unroll
        for (int dt = 0; dt < 4; ++dt)
            Oacc[dt] = mfma16(fv[pair][dt], pb, Oacc[dt]);
    }
}

__global__ __launch_bounds__(256, 4)
void attn_kernel(const u16* __restrict__ Q, const u16* __restrict__ Kb,
                 const u16* __restrict__ Vt, u16* __restrict__ O) {
    __shared__ alignas(16) u16 Ks[2][64 * KST];
    __shared__ alignas(16) u16 Vs[2][64 * KST];

    // Decode: bid[2:0]=xcd (hosts bh with bh&7==xcd), bid[4:3]=bh>>3,
    // bid[9:5]=31-qt (longest q-tile dispatched first).
    const int bid = (int)blockIdx.x;
    const int j2 = bid >> 3;
    const int qt = 31 - (j2 >> 2);
    const int bh = (bid & 7) + 8 * (j2 & 3);
    const int jmax = qt;

    const int tid = threadIdx.x;
    const int wave = tid >> 6, lane = tid & 63;
    const int quad = lane >> 4, l16 = lane & 15;

    const u16* Qh = Q  + (size_t)bh * TT * DH;
    const u16* Kh = Kb + (size_t)bh * TT * DH;
    const u16* Vh = Vt + (size_t)bh * DH * TT;

    const int row = qt * 64 + wave * 16;

    // Q fragments (B-operand: n = l16 = q, k = quad*8+j over d)
    bf16x8 fq[2];
    fq[0] = *(const bf16x8*)&Qh[(row + l16) * DH + quad * 8];
    fq[1] = *(const bf16x8*)&Qh[(row + l16) * DH + 32 + quad * 8];

    // ones A-fragment: row (m) index = l16, so lanes with l16==0 hold the
    // all-ones row 0; C row 0 = quad0/reg0 collects sum(P) per q-col.
    bf16x8 fone;
    {
        const __bf16 ov = (l16 == 0) ? (__bf16)1.f : (__bf16)0.f;
        #pragma unroll
        for (int j = 0; j < 8; ++j) fone[j] = ov;
    }

    f32x4 Oa[4] = {}, lacc = {};
    float m_i = -INFINITY;

    // Chunk staging: thread i covers 16B at row (i>>3), col (i&7)*8, +row32.
    const int trow = tid >> 3;
    const int ic   = tid & 7;            // 8-key group index
    const int tcol = ic * 8;
    // V pair-permuted destination column for this thread's 8 keys:
    //   keys 8*ic..8*ic+7 -> cols c1..c1+3 and c1+8..c1+11
    const int vc1 = 32 * (ic >> 2) + 16 * (ic & 1) + 4 * ((ic & 3) >> 1);
    uint4 kr0, kr1, vr0, vr1;

    auto load_chunk = [&](int j) {
        const u16* ks = Kh + (size_t)j * 64 * DH;
        kr0 = *(const uint4*)&ks[trow * DH + tcol];
        kr1 = *(const uint4*)&ks[(trow + 32) * DH + tcol];
        const u16* vs = Vh + (size_t)j * 64;
        vr0 = *(const uint4*)&vs[(size_t)trow * TT + tcol];
        vr1 = *(const uint4*)&vs[(size_t)(trow + 32) * TT + tcol];
    };
    auto write_chunk = [&](int buf) {
        *(uint4*)&Ks[buf][trow * KST + tcol]        = kr0;
        *(uint4*)&Ks[buf][(trow + 32) * KST + tcol] = kr1;
        // V: split each 16B into two 8B halves at permuted columns
        *(uint2*)&Vs[buf][trow * KST + vc1]            = *(const uint2*)&vr0;
        *(uint2*)&Vs[buf][trow * KST + vc1 + 8]        = *((const uint2*)&vr0 + 1);
        *(uint2*)&Vs[buf][(trow + 32) * KST + vc1]     = *(const uint2*)&vr1;
        *(uint2*)&Vs[buf][(trow + 32) * KST + vc1 + 8] = *((const uint2*)&vr1 + 1);
    };

    load_chunk(0);
    write_chunk(0);

    for (int j = 0; j <= jmax; ++j) {
        const int cur = j & 1;
        __syncthreads();                    // buf[cur] staged & visible
        if (j < jmax) load_chunk(j + 1);    // loads fly during compute

        // Hoist K/V fragments (issued early; compiler inserts lgkm waits)
        bf16x8 fk[4][2], fv[2][4];
        #pragma unroll
        for (int nt = 0; nt < 4; ++nt) {
            fk[nt][0] = *(const bf16x8*)&Ks[cur][(nt * 16 + l16) * KST + quad * 8];
            fk[nt][1] = *(const bf16x8*)&Ks[cur][(nt * 16 + l16) * KST + 32 + quad * 8];
        }
        #pragma unroll
        for (int pair = 0; pair < 2; ++pair)
            #pragma unroll
            for (int dt = 0; dt < 4; ++dt)
                fv[pair][dt] = *(const bf16x8*)
                    &Vs[cur][(dt * 16 + l16) * KST + pair * 32 + quad * 8];

        attn_step(fk, fv, fone, fq, Oa, lacc, m_i, (j == qt),
                  wave, quad, l16);
        if (j < jmax) write_chunk(cur ^ 1); // after all buf[cur^1] readers done
    }

    // l for this lane's q-col lives in the quad-0 lane of the same column.
    const float lrow = __shfl(lacc[0], l16, 64);
    const float r_i = 1.f / lrow;

    // Epilogue: O^T rows d = dt*16+quad*4+reg, col q = l16; write (B,T,C).
    const int b = bh >> 4, h = bh & 15;
    #pragma unroll
    for (int dt = 0; dt < 4; ++dt) {
        u16 oa[4];
        #pragma unroll
        for (int reg = 0; reg < 4; ++reg)
            oa[reg] = f2bf(Oa[dt][reg] * r_i);
        *(uint2*)&O[((size_t)(b * TT + row + l16)) * CD + h * DH + dt * 16 + quad * 4] =
            *(const uint2*)oa;
    }
}

// ---------------------------------------------------------------------------
extern "C" void kernel_launch(void* const* d_in, const int* in_sizes, int n_in,
                              void* d_out, int out_size, void* d_ws, size_t ws_size,
                              hipStream_t stream) {
    (void)in_sizes; (void)n_in; (void)out_size; (void)ws_size;
    const float* x    = (const float*)d_in[0];   // (4096, 1024) fp32
    const float* Wqkv = (const float*)d_in[1];   // (1024, 3072) fp32
    const float* Wo   = (const float*)d_in[2];   // (1024, 1024) fp32
    float* out = (float*)d_out;                  // (4096, 1024) fp32

    char* ws = (char*)d_ws;
    u16* xb    = (u16*)(ws + 0);                    // 4096x1024  (8 MB)
    u16* WqkvT = (u16*)(ws + (8u  << 20));          // 3072x1024  (6 MB)
    u16* WoT   = (u16*)(ws + (14u << 20));          // 1024x1024  (2 MB)
    u16* Qb    = (u16*)(ws + (16u << 20));          // (B,H,T,64) (8 MB)
    u16* Kb    = (u16*)(ws + (24u << 20));          // (B,H,T,64) (8 MB)
    u16* Vt    = (u16*)(ws + (32u << 20));          // (B,H,64,T) (8 MB)
    u16* attn  = (u16*)(ws + (40u << 20));          // (B,T,C)    (8 MB)

    prep_kernel<<<6144, 256, 0, stream>>>(x, xb, Wqkv, WqkvT, Wo, WoT);

    // qkv = x @ W_qkv (3-deep pipelined, 128x128): grid 768 = 3 blocks/CU.
    gemm_db<1, 128, 128, 24><<<768, 256, 0, stream>>>(
        xb, WqkvT, Qb, Kb, Vt, nullptr, BT, 3072, CD);

    // attn: 1024 single-q-tile blocks, longest-first, bh->XCD locality.
    attn_kernel<<<1024, 256, 0, stream>>>(Qb, Kb, Vt, attn);

    // out = attn @ W_o (3-deep pipelined, 64x64): grid 1024 = 4 blocks/CU.
    gemm_db<0, 64, 64, 16><<<1024, 256, 0, stream>>>(
        attn, WoT, nullptr, nullptr, nullptr, out, BT, CD, CD);
}